// Round 1
// baseline (1330.617 us; speedup 1.0000x reference)
//
#include <hip/hip_runtime.h>
#include <math.h>

#define D 128

typedef short bf16x8 __attribute__((ext_vector_type(8)));
typedef float f32x4 __attribute__((ext_vector_type(4)));

// ---------------------------------------------------------------- bf16 helpers (RNE)
__device__ __forceinline__ ushort f2b(float f) {
    union { float f; unsigned u; } v; v.f = f;
    unsigned r = v.u + 0x7FFFu + ((v.u >> 16) & 1u);
    return (ushort)(r >> 16);
}
__device__ __forceinline__ float b2f(ushort b) {
    union { unsigned u; float f; } v; v.u = ((unsigned)b) << 16;
    return v.f;
}
// async global->LDS, 16B per lane; LDS dest = wave-uniform base + lane*16
__device__ __forceinline__ void gl_lds16(const void* g, void* l) {
    __builtin_amdgcn_global_load_lds(
        (const __attribute__((address_space(1))) void*)g,
        (__attribute__((address_space(3))) void*)l, 16, 0, 0);
}
__device__ __forceinline__ int lower_bound_i(const int* __restrict__ a, int n, int v) {
    int lo = 0, hi = n;
    while (lo < hi) { int m = (lo + hi) >> 1; if (a[m] < v) lo = m + 1; else hi = m; }
    return lo;
}

// ---------------------------------------------------------------- CSR build (dst fixed per call)
__global__ void count_kernel(const int* __restrict__ dst, int* __restrict__ cnt, int E) {
    int e = blockIdx.x * blockDim.x + threadIdx.x;
    if (e < E) atomicAdd(&cnt[dst[e]], 1);
}

__global__ void scan_kernel(const int* __restrict__ cnt, int* __restrict__ offs, int N) {
    __shared__ int part[1024];
    const int t = threadIdx.x;
    const int chunk = (N + 1023) >> 10;
    int lo = t * chunk; if (lo > N) lo = N;
    int hi = lo + chunk; if (hi > N) hi = N;
    int s = 0;
    for (int i = lo; i < hi; ++i) s += cnt[i];
    part[t] = s;
    __syncthreads();
    if (t == 0) {
        int a = 0;
        for (int i = 0; i < 1024; ++i) { int v = part[i]; part[i] = a; a += v; }
        offs[N] = a;
    }
    __syncthreads();
    int a = part[t];
    for (int i = lo; i < hi; ++i) { offs[i] = a; a += cnt[i]; }
}

__global__ void scatter_kernel(const int* __restrict__ dst, const int* __restrict__ offs,
                               int* __restrict__ fill, int* __restrict__ csr, int E) {
    int e = blockIdx.x * blockDim.x + threadIdx.x;
    if (e < E) {
        int d = dst[e];
        int p = offs[d] + atomicAdd(&fill[d], 1);
        csr[p] = e;
    }
}

// ---------------------------------------------------------------- fused prep:
// [0,c0)  edge fp32->bf16 in-place (row e bf16 in first 256B of 512B slot)
// [c0,c1) node f2b, [c1,c2) u f2b,
// [c2,c3) We split-transpose -> Bt12 (W1|W2, 256x128) + W3t (128x128),
// [c3,c4) Wn transpose
__global__ void prep_kernel(
    float* __restrict__ edge,
    const float* __restrict__ node, ushort* __restrict__ node_bf,
    const float* __restrict__ u, ushort* __restrict__ u_bf,
    const float* __restrict__ We_w, ushort* __restrict__ Bt12, ushort* __restrict__ W3t,
    const float* __restrict__ Wn_w, ushort* __restrict__ Wnt,
    int N, int G, int E)
{
    const int gid = blockIdx.x * 256 + threadIdx.x;
    const int c0 = E * 32;
    const int c1 = c0 + N * D / 4;
    const int c2 = c1 + G * D / 4;
    const int c3 = c2 + 512 * D;
    const int c4 = c3 + 384 * D;
    if (gid < c0) {
        int row = gid >> 5, q = gid & 31;
        float4 v = *(const float4*)(edge + (size_t)row * D + q * 4);
        ushort4 o; o.x = f2b(v.x); o.y = f2b(v.y); o.z = f2b(v.z); o.w = f2b(v.w);
        *(ushort4*)((ushort*)edge + (size_t)row * 256 + q * 4) = o;
    } else if (gid < c1) {
        int i = (gid - c0) * 4;
        float4 v = *(const float4*)(node + i);
        ushort4 o; o.x = f2b(v.x); o.y = f2b(v.y); o.z = f2b(v.z); o.w = f2b(v.w);
        *(ushort4*)(node_bf + i) = o;
    } else if (gid < c2) {
        int i = (gid - c1) * 4;
        float4 v = *(const float4*)(u + i);
        ushort4 o; o.x = f2b(v.x); o.y = f2b(v.y); o.z = f2b(v.z); o.w = f2b(v.w);
        *(ushort4*)(u_bf + i) = o;
    } else if (gid < c3) {
        int i = gid - c2;              // We[k][n], k=0..511, n=0..127
        int k = i >> 7, n = i & 127;
        if (k < 384) {
            ushort b = f2b(We_w[i]);
            if (k < 256)               // Bt12[(half*128+n)][k&127]
                Bt12[(((size_t)((k >> 7) << 7) + n) << 7) + (k & 127)] = b;
            else                       // W3t[n][k-256]
                W3t[((size_t)n << 7) + (k - 256)] = b;
        }
    } else if (gid < c4) {
        int i = gid - c3;              // Wn[k][n] -> Wnt[n][k], K=384
        int k = i >> 7, n = i & 127;
        Wnt[(size_t)n * 384 + k] = f2b(Wn_w[i]);
    }
}

// ---------------------------------------------------------------- u projection: up = u @ W4 + We_b (f32)
__global__ void uproj_kernel(const float* __restrict__ u, const float* __restrict__ We_w,
                             const float* __restrict__ We_b, float* __restrict__ upf)
{
    __shared__ float us[128];
    const int g = blockIdx.x;
    const int j = threadIdx.x;
    us[j] = u[g * D + j];
    __syncthreads();
    float s = We_b[j];
    for (int k = 0; k < 128; ++k) s += us[k] * We_w[(size_t)(384 + k) * D + j];
    upf[g * D + j] = s;
}

// ---------------------------------------------------------------- node projection GEMM:
// npf[n][0:128] = node@W1, npf[n][128:256] = node@W2  (f32, no bias/relu)
// tile 128 rows x 256 cols, K=128. 4 waves (2M x 2N), each 64x128 (acc[4][8]).
__global__ __launch_bounds__(256) void nproj_gemm(
    const ushort* __restrict__ node_bf, const ushort* __restrict__ Bt12,
    float* __restrict__ npf, int N)
{
    __shared__ ushort As[128 * 32];   // 8 KB
    __shared__ ushort Bs[256 * 32];   // 16 KB

    const int tid = threadIdx.x;
    const int w = tid >> 6, l = tid & 63;
    const int n0 = blockIdx.x * 128;

    f32x4 acc[4][8];
#pragma unroll
    for (int i = 0; i < 4; ++i)
#pragma unroll
        for (int j = 0; j < 8; ++j) acc[i][j] = (f32x4)0.0f;

    const int wm = (w >> 1) * 64, wn = (w & 1) * 128;
    const int srow = l >> 2;
    const int part = (l & 3) * 8;

    for (int c = 0; c < 4; ++c) {
        const int kl = c * 32;
#pragma unroll
        for (int t = 0; t < 2; ++t) {   // A: 8 segs of 16 rows
            const int s = w + t * 4;
            int n = n0 + s * 16 + srow; if (n >= N) n = N - 1;
            gl_lds16(node_bf + (size_t)n * D + kl + part, &As[s * 512]);
        }
#pragma unroll
        for (int t = 0; t < 4; ++t) {   // B: 16 segs of 16 n-rows
            const int s = w * 4 + t;
            const int n = s * 16 + srow;
            gl_lds16(Bt12 + (size_t)n * 128 + kl + part, &Bs[s * 512]);
        }
        __syncthreads();

        bf16x8 af[4], bfr[8];
#pragma unroll
        for (int i = 0; i < 4; ++i)
            af[i] = *(const bf16x8*)&As[(wm + i * 16 + (l & 15)) * 32 + (l >> 4) * 8];
#pragma unroll
        for (int j = 0; j < 8; ++j)
            bfr[j] = *(const bf16x8*)&Bs[(wn + j * 16 + (l & 15)) * 32 + (l >> 4) * 8];
#pragma unroll
        for (int i = 0; i < 4; ++i)
#pragma unroll
            for (int j = 0; j < 8; ++j)
                acc[i][j] = __builtin_amdgcn_mfma_f32_16x16x32_bf16(af[i], bfr[j], acc[i][j], 0, 0, 0);
        __syncthreads();
    }

#pragma unroll
    for (int i = 0; i < 4; ++i) {
#pragma unroll
        for (int r = 0; r < 4; ++r) {
            const int m = wm + i * 16 + (l >> 4) * 4 + r;
            const int n = n0 + m;
            if (n < N) {
#pragma unroll
                for (int j = 0; j < 8; ++j)
                    npf[(size_t)n * 256 + wn + j * 16 + (l & 15)] = acc[i][j][r];
            }
        }
    }
}

// ---------------------------------------------------------------- edge update GEMM (MFMA bf16), K=128
// e' = relu(e@W3 + np1[src] + np2[dst] + up[batch[src]])   (up includes bias)
// tile 256 edges x 128 cols. 4 waves, each 64 rows x 128 cols (acc[4][8]).
__global__ __launch_bounds__(256, 2) void edge_gemm(
    ushort* __restrict__ edge_u,
    const float* __restrict__ npf, const float* __restrict__ upf,
    const int* __restrict__ src, const int* __restrict__ dst,
    const int* __restrict__ batch,
    const ushort* __restrict__ W3t, int E)
{
    __shared__ ushort As[256 * 32];   // 16 KB
    __shared__ ushort Bs[128 * 32];   // 8 KB
    __shared__ int rs[256], rd[256], rb[256];

    const int tid = threadIdx.x;
    const int w = tid >> 6, l = tid & 63;
    const int e0 = blockIdx.x * 256;

    {
        int e = e0 + tid; if (e >= E) e = E - 1;
        int s = src[e];
        rs[tid] = s; rd[tid] = dst[e]; rb[tid] = batch[s];
    }

    f32x4 acc[4][8];
#pragma unroll
    for (int i = 0; i < 4; ++i)
#pragma unroll
        for (int j = 0; j < 8; ++j) acc[i][j] = (f32x4)0.0f;

    const int wm = w * 64;             // wave's M offset
    const int srow = l >> 2;           // 0..15 within seg
    const int part = (l & 3) * 8;      // ushort offset within 64B row chunk

    __syncthreads();                   // rs/rd/rb visible

    for (int c = 0; c < 4; ++c) {
        const int kl = c * 32;         // k offset within 128-ushort row

#pragma unroll
        for (int t = 0; t < 4; ++t) {  // A: 4 segs of 16 edge rows per wave (16 segs)
            const int s = w * 4 + t;
            int e = e0 + s * 16 + srow; if (e >= E) e = E - 1;
            gl_lds16(edge_u + (size_t)e * 256 + kl + part, &As[s * 512]);
        }
#pragma unroll
        for (int t = 0; t < 2; ++t) {  // B: 2 segs of 16 cols per wave (8 segs)
            const int s = w + t * 4;
            const int n = s * 16 + srow;
            gl_lds16(W3t + (size_t)n * 128 + kl + part, &Bs[s * 512]);
        }
        __syncthreads();               // drains vmcnt -> LDS ready

        bf16x8 af[4], bfr[8];
#pragma unroll
        for (int i = 0; i < 4; ++i)
            af[i] = *(const bf16x8*)&As[(wm + i * 16 + (l & 15)) * 32 + (l >> 4) * 8];
#pragma unroll
        for (int j = 0; j < 8; ++j)
            bfr[j] = *(const bf16x8*)&Bs[(j * 16 + (l & 15)) * 32 + (l >> 4) * 8];
#pragma unroll
        for (int i = 0; i < 4; ++i)
#pragma unroll
            for (int j = 0; j < 8; ++j)
                acc[i][j] = __builtin_amdgcn_mfma_f32_16x16x32_bf16(af[i], bfr[j], acc[i][j], 0, 0, 0);
        __syncthreads();               // compute done before next overwrite
    }

    // epilogue: + gathered node/global projections, relu, bf16 store
    const int cc = l & 15;
#pragma unroll
    for (int i = 0; i < 4; ++i) {
#pragma unroll
        for (int r = 0; r < 4; ++r) {
            const int m = wm + i * 16 + (l >> 4) * 4 + r;
            const int e = e0 + m;
            if (e < E) {
                const float* p1 = npf + (size_t)rs[m] * 256;
                const float* p2 = npf + (size_t)rd[m] * 256 + 128;
                const float* pu = upf + (size_t)rb[m] * D;
                ushort* ep = edge_u + (size_t)e * 256;
#pragma unroll
                for (int j = 0; j < 8; ++j) {
                    const int col = j * 16 + cc;
                    float v = acc[i][j][r] + p1[col] + p2[col] + pu[col];
                    ep[col] = f2b(fmaxf(v, 0.0f));
                }
            }
        }
    }
}

// ---------------------------------------------------------------- ebar gather (CSR, vectorized)
// 8 nodes/block, 32 lanes/node, ushort4 (4 cols) per lane.
__global__ void gather_ebar(const ushort* __restrict__ edge_u, const int* __restrict__ offs,
                            const int* __restrict__ csr, ushort* __restrict__ ebar_bf, int N)
{
    int n = blockIdx.x * 8 + (threadIdx.x >> 5);
    int q = threadIdx.x & 31;
    if (n >= N) return;
    int lo = offs[n], hi = offs[n + 1];
    float s0 = 0.0f, s1 = 0.0f, s2 = 0.0f, s3 = 0.0f;
    for (int j = lo; j < hi; ++j) {
        int e = csr[j];
        ushort4 v = *(const ushort4*)(edge_u + (size_t)e * 256 + q * 4);
        s0 += b2f(v.x); s1 += b2f(v.y); s2 += b2f(v.z); s3 += b2f(v.w);
    }
    float inv = 1.0f / (float)max(hi - lo, 1);
    ushort4 o; o.x = f2b(s0 * inv); o.y = f2b(s1 * inv); o.z = f2b(s2 * inv); o.w = f2b(s3 * inv);
    *(ushort4*)(ebar_bf + (size_t)n * D + q * 4) = o;
}

// ---------------------------------------------------------------- node update GEMM (MFMA bf16), K=384
__global__ __launch_bounds__(256) void node_gemm(
    ushort* __restrict__ node_bf, const ushort* __restrict__ ebar_bf,
    const ushort* __restrict__ u_bf, const int* __restrict__ batch,
    const ushort* __restrict__ Wt, const float* __restrict__ bias, int N)
{
    __shared__ ushort As[128 * 32];
    __shared__ ushort Bs[128 * 32];
    __shared__ int rb[128];

    const int tid = threadIdx.x;
    const int w = tid >> 6, l = tid & 63;
    const int n0 = blockIdx.x * 128;

    if (tid < 128) {
        int n = n0 + tid; if (n >= N) n = N - 1;
        rb[tid] = batch[n];
    }

    f32x4 acc[4][4];
#pragma unroll
    for (int i = 0; i < 4; ++i)
#pragma unroll
        for (int j = 0; j < 4; ++j) acc[i][j] = (f32x4)0.0f;

    const int wm = (w >> 1) * 64, wn = (w & 1) * 64;
    float bj4[4];
#pragma unroll
    for (int j = 0; j < 4; ++j) bj4[j] = bias[wn + j * 16 + (l & 15)];

    const int srow = l >> 2;
    const int part = (l & 3) * 8;

    __syncthreads();

    for (int c = 0; c < 12; ++c) {
        const int srcsel = c >> 2;
        const int kl = (c & 3) * 32;

#pragma unroll
        for (int t = 0; t < 2; ++t) {
            const int s = w + t * 4;
            const int row = s * 16 + srow;
            int n = n0 + row; if (n >= N) n = N - 1;
            const ushort* gp;
            if (srcsel == 0)      gp = node_bf + (size_t)n * D + kl + part;
            else if (srcsel == 1) gp = ebar_bf + (size_t)n * D + kl + part;
            else                  gp = u_bf + (size_t)rb[row] * D + kl + part;
            gl_lds16(gp, &As[s * 512]);
        }
#pragma unroll
        for (int t = 0; t < 2; ++t) {
            const int s = w + t * 4;
            const int n = s * 16 + srow;
            gl_lds16(Wt + (size_t)n * 384 + c * 32 + part, &Bs[s * 512]);
        }
        __syncthreads();

        bf16x8 af[4], bfr[4];
#pragma unroll
        for (int i = 0; i < 4; ++i)
            af[i] = *(const bf16x8*)&As[(wm + i * 16 + (l & 15)) * 32 + (l >> 4) * 8];
#pragma unroll
        for (int j = 0; j < 4; ++j)
            bfr[j] = *(const bf16x8*)&Bs[(wn + j * 16 + (l & 15)) * 32 + (l >> 4) * 8];
#pragma unroll
        for (int i = 0; i < 4; ++i)
#pragma unroll
            for (int j = 0; j < 4; ++j)
                acc[i][j] = __builtin_amdgcn_mfma_f32_16x16x32_bf16(af[i], bfr[j], acc[i][j], 0, 0, 0);
        __syncthreads();
    }

#pragma unroll
    for (int i = 0; i < 4; ++i) {
#pragma unroll
        for (int r = 0; r < 4; ++r) {
            const int m = wm + i * 16 + (l >> 4) * 4 + r;
            const int n = n0 + m;
            if (n < N) {
#pragma unroll
                for (int j = 0; j < 4; ++j) {
                    float v = fmaxf(acc[i][j][r] + bj4[j], 0.0f);
                    node_bf[(size_t)n * D + wn + j * 16 + (l & 15)] = f2b(v);
                }
            }
        }
    }
}

// ---------------------------------------------------------------- per-graph sums, phase 1
__global__ void reduce_partial(
    const ushort* __restrict__ node_bf, const ushort* __restrict__ ebar_bf,
    const int* __restrict__ batch,
    float* __restrict__ nsum, float* __restrict__ esum, int N)
{
    const int col = threadIdx.x & 127;
    const int half = threadIdx.x >> 7;
    const int r0 = blockIdx.x * 128;
    float sn = 0.0f, se = 0.0f;
    int cur = -1;
    for (int ri = half; ri < 128; ri += 2) {
        int r = r0 + ri;
        if (r >= N) break;
        int g = batch[r];
        if (g != cur) {
            if (cur >= 0) {
                atomicAdd(&nsum[cur * D + col], sn);
                atomicAdd(&esum[cur * D + col], se);
            }
            cur = g; sn = 0.0f; se = 0.0f;
        }
        sn += b2f(node_bf[(size_t)r * D + col]);
        se += b2f(ebar_bf[(size_t)r * D + col]);
    }
    if (cur >= 0) {
        atomicAdd(&nsum[cur * D + col], sn);
        atomicAdd(&esum[cur * D + col], se);
    }
}

// ---------------------------------------------------------------- phase 2 + global update fused
__global__ void finalize_global(
    float* __restrict__ nsum, float* __restrict__ esum,
    const int* __restrict__ batch,
    float* __restrict__ nmean, float* __restrict__ emean,
    float* __restrict__ u, ushort* __restrict__ u_bf,
    const float* __restrict__ W, const float* __restrict__ bias, int N)
{
    __shared__ float gin[384];
    __shared__ int cnt_s;
    const int g = blockIdx.x;
    const int j = threadIdx.x;   // 0..127
    if (j == 0) {
        int lo = lower_bound_i(batch, N, g);
        int hi = lower_bound_i(batch, N, g + 1);
        cnt_s = hi - lo;
    }
    __syncthreads();
    float inv = 1.0f / (float)max(cnt_s, 1);
    float nm = nsum[g * D + j] * inv;
    float em = esum[g * D + j] * inv;
    nmean[g * D + j] = nm;
    emean[g * D + j] = em;
    nsum[g * D + j] = 0.0f;
    esum[g * D + j] = 0.0f;
    gin[j] = nm; gin[128 + j] = em; gin[256 + j] = u[g * D + j];
    __syncthreads();
    float s = bias[j];
    for (int k = 0; k < 384; ++k) s += gin[k] * W[(size_t)k * D + j];
    float v = fmaxf(s, 0.0f);
    u[g * D + j] = v;
    u_bf[g * D + j] = f2b(v);
}

// ---------------------------------------------------------------- readout
__global__ void out_kernel(
    const float* __restrict__ nmean, const float* __restrict__ emean,
    const float* __restrict__ u, const int* __restrict__ batch,
    const float* __restrict__ lw, const float* __restrict__ lb,
    float* __restrict__ out, int N, int NC)
{
    __shared__ float pin[384];
    __shared__ int cntg;
    const int g = blockIdx.x;
    const int t = threadIdx.x;   // 0..383
    if (t == 0) {
        int lo = lower_bound_i(batch, N, g);
        int hi = lower_bound_i(batch, N, g + 1);
        cntg = hi - lo;
    }
    __syncthreads();
    if (t < 128)       pin[t] = nmean[g * D + t];
    else if (t < 256)  pin[t] = emean[g * D + (t - 128)];
    else               pin[t] = (cntg > 0) ? u[g * D + (t - 256)] : 0.0f;
    __syncthreads();
    int c = t >> 5, wv = t & 31;
    if (c < NC) {
        float s = 0.0f;
        for (int k = wv; k < 384; k += 32) s += pin[k] * lw[(size_t)k * NC + c];
#pragma unroll
        for (int off = 16; off > 0; off >>= 1) s += __shfl_down(s, off, 32);
        if (wv == 0) out[g * NC + c] = s + lb[c];
    }
}

// ---------------------------------------------------------------- driver
extern "C" void kernel_launch(void* const* d_in, const int* in_sizes, int n_in,
                              void* d_out, int out_size, void* d_ws, size_t ws_size,
                              hipStream_t stream) {
    float* node = (float*)d_in[0];
    float* edge = (float*)d_in[1];
    float* u    = (float*)d_in[2];
    const int* eidx  = (const int*)d_in[3];
    const int* batch = (const int*)d_in[4];
    const float* We_w = (const float*)d_in[5];
    const float* We_b = (const float*)d_in[6];
    const float* Wn_w = (const float*)d_in[7];
    const float* Wn_b = (const float*)d_in[8];
    const float* Wg_w = (const float*)d_in[9];
    const float* Wg_b = (const float*)d_in[10];
    const float* lin_w = (const float*)d_in[11];
    const float* lin_b = (const float*)d_in[12];

    const int N = in_sizes[0] / D;        // 50000
    const int E = in_sizes[3] / 2;        // 600000
    const int G = in_sizes[2] / D;        // 64
    const int NC = out_size / G;          // 10
    const int* src = eidx;
    const int* dst = eidx + E;

    // workspace carve-up (256B-aligned chunks); cnt..esum contiguous for single memset
    char* p = (char*)d_ws;
    auto carve = [&](size_t bytes) { void* r = p; p += (bytes + 255) & ~(size_t)255; return r; };
    int*    cnt     = (int*)carve((size_t)N * 4);
    int*    fill    = (int*)carve((size_t)N * 4);
    float*  nsum    = (float*)carve((size_t)G * D * 4);
    float*  esum    = (float*)carve((size_t)G * D * 4);
    size_t  zspan   = (size_t)(p - (char*)cnt);
    int*    offs    = (int*)carve((size_t)(N + 1) * 4);
    int*    csr     = (int*)carve((size_t)E * 4);
    ushort* node_bf = (ushort*)carve((size_t)N * D * 2);
    ushort* ebar_bf = (ushort*)carve((size_t)N * D * 2);
    ushort* u_bf    = (ushort*)carve((size_t)G * D * 2);
    ushort* Bt12    = (ushort*)carve((size_t)256 * 128 * 2);
    ushort* W3t     = (ushort*)carve((size_t)128 * 128 * 2);
    ushort* Wnt     = (ushort*)carve((size_t)384 * D * 2);
    float*  nmean   = (float*)carve((size_t)G * D * 4);
    float*  emean   = (float*)carve((size_t)G * D * 4);
    float*  upf     = (float*)carve((size_t)G * D * 4);
    float*  npf     = (float*)carve((size_t)N * 256 * 4);

    ushort* edge_u = (ushort*)edge;  // bf16-in-place, row stride 256 ushorts

    hipMemsetAsync(cnt, 0, zspan, stream);   // cnt, fill, nsum, esum

    // CSR build (dst fixed per call)
    count_kernel<<<(E + 255) / 256, 256, 0, stream>>>(dst, cnt, E);
    scan_kernel<<<1, 1024, 0, stream>>>(cnt, offs, N);
    scatter_kernel<<<(E + 255) / 256, 256, 0, stream>>>(dst, offs, fill, csr, E);

    // fused conversions / transposes
    const int prep_units = E * 32 + N * D / 4 + G * D / 4 + 512 * D + 384 * D;
    prep_kernel<<<(prep_units + 255) / 256, 256, 0, stream>>>(
        edge, node, node_bf, u, u_bf, We_w, Bt12, W3t, Wn_w, Wnt, N, G, E);

    const int edge_blocks = (E + 255) / 256;
    const int node_blocks = (N + 127) / 128;
    const int proj_blocks = (N + 127) / 128;
    const int red_blocks  = (N + 127) / 128;

    for (int pass = 0; pass < 3; ++pass) {
        uproj_kernel<<<G, 128, 0, stream>>>(u, We_w, We_b, upf);
        nproj_gemm<<<proj_blocks, 256, 0, stream>>>(node_bf, Bt12, npf, N);
        edge_gemm<<<edge_blocks, 256, 0, stream>>>(edge_u, npf, upf, src, dst, batch,
                                                   W3t, E);
        gather_ebar<<<(N + 7) / 8, 256, 0, stream>>>(edge_u, offs, csr, ebar_bf, N);
        node_gemm<<<node_blocks, 256, 0, stream>>>(node_bf, ebar_bf, u_bf, batch,
                                                   Wnt, Wn_b, N);
        reduce_partial<<<red_blocks, 256, 0, stream>>>(node_bf, ebar_bf, batch, nsum, esum, N);
        finalize_global<<<G, 128, 0, stream>>>(nsum, esum, batch, nmean, emean,
                                               u, u_bf, Wg_w, Wg_b, N);
    }
    out_kernel<<<G, 384, 0, stream>>>(nmean, emean, u, batch, lin_w, lin_b,
                                      (float*)d_out, N, NC);
}

// Round 2
// 1328.818 us; speedup vs baseline: 1.0014x; 1.0014x over previous
//
#include <hip/hip_runtime.h>
#include <math.h>

#define D 128

typedef short bf16x8 __attribute__((ext_vector_type(8)));
typedef float f32x4 __attribute__((ext_vector_type(4)));
typedef ushort ushort8 __attribute__((ext_vector_type(8)));

// ---------------------------------------------------------------- bf16 helpers (RNE)
__device__ __forceinline__ ushort f2b(float f) {
    union { float f; unsigned u; } v; v.f = f;
    unsigned r = v.u + 0x7FFFu + ((v.u >> 16) & 1u);
    return (ushort)(r >> 16);
}
__device__ __forceinline__ float b2f(ushort b) {
    union { unsigned u; float f; } v; v.u = ((unsigned)b) << 16;
    return v.f;
}
// async global->LDS, 16B per lane; LDS dest = wave-uniform base + lane*16
__device__ __forceinline__ void gl_lds16(const void* g, void* l) {
    __builtin_amdgcn_global_load_lds(
        (const __attribute__((address_space(1))) void*)g,
        (__attribute__((address_space(3))) void*)l, 16, 0, 0);
}
__device__ __forceinline__ int lower_bound_i(const int* __restrict__ a, int n, int v) {
    int lo = 0, hi = n;
    while (lo < hi) { int m = (lo + hi) >> 1; if (a[m] < v) lo = m + 1; else hi = m; }
    return lo;
}

// ---------------------------------------------------------------- CSR build (dst fixed per call)
__global__ void count_kernel(const int* __restrict__ dst, int* __restrict__ cnt, int E) {
    int e = blockIdx.x * blockDim.x + threadIdx.x;
    if (e < E) atomicAdd(&cnt[dst[e]], 1);
}

__global__ void scan_kernel(const int* __restrict__ cnt, int* __restrict__ offs, int N) {
    __shared__ int part[1024];
    const int t = threadIdx.x;
    const int chunk = (N + 1023) >> 10;
    int lo = t * chunk; if (lo > N) lo = N;
    int hi = lo + chunk; if (hi > N) hi = N;
    int s = 0;
    for (int i = lo; i < hi; ++i) s += cnt[i];
    part[t] = s;
    __syncthreads();
    if (t == 0) {
        int a = 0;
        for (int i = 0; i < 1024; ++i) { int v = part[i]; part[i] = a; a += v; }
        offs[N] = a;
    }
    __syncthreads();
    int a = part[t];
    for (int i = lo; i < hi; ++i) { offs[i] = a; a += cnt[i]; }
}

__global__ void scatter_kernel(const int* __restrict__ dst, const int* __restrict__ offs,
                               int* __restrict__ fill, int* __restrict__ csr, int E) {
    int e = blockIdx.x * blockDim.x + threadIdx.x;
    if (e < E) {
        int d = dst[e];
        int p = offs[d] + atomicAdd(&fill[d], 1);
        csr[p] = e;
    }
}

// ---------------------------------------------------------------- fused prep:
// [0,c0)  edge fp32->bf16 in-place (row e bf16 in first 256B of 512B slot)
// [c0,c1) node f2b, [c1,c2) u f2b,
// [c2,c3) We split-transpose -> Bt12 (W1|W2, 256x128) + W3t (128x128),
// [c3,c4) Wn transpose
__global__ void prep_kernel(
    float* __restrict__ edge,
    const float* __restrict__ node, ushort* __restrict__ node_bf,
    const float* __restrict__ u, ushort* __restrict__ u_bf,
    const float* __restrict__ We_w, ushort* __restrict__ Bt12, ushort* __restrict__ W3t,
    const float* __restrict__ Wn_w, ushort* __restrict__ Wnt,
    int N, int G, int E)
{
    const int gid = blockIdx.x * 256 + threadIdx.x;
    const int c0 = E * 32;
    const int c1 = c0 + N * D / 4;
    const int c2 = c1 + G * D / 4;
    const int c3 = c2 + 512 * D;
    const int c4 = c3 + 384 * D;
    if (gid < c0) {
        int row = gid >> 5, q = gid & 31;
        float4 v = *(const float4*)(edge + (size_t)row * D + q * 4);
        ushort4 o; o.x = f2b(v.x); o.y = f2b(v.y); o.z = f2b(v.z); o.w = f2b(v.w);
        *(ushort4*)((ushort*)edge + (size_t)row * 256 + q * 4) = o;
    } else if (gid < c1) {
        int i = (gid - c0) * 4;
        float4 v = *(const float4*)(node + i);
        ushort4 o; o.x = f2b(v.x); o.y = f2b(v.y); o.z = f2b(v.z); o.w = f2b(v.w);
        *(ushort4*)(node_bf + i) = o;
    } else if (gid < c2) {
        int i = (gid - c1) * 4;
        float4 v = *(const float4*)(u + i);
        ushort4 o; o.x = f2b(v.x); o.y = f2b(v.y); o.z = f2b(v.z); o.w = f2b(v.w);
        *(ushort4*)(u_bf + i) = o;
    } else if (gid < c3) {
        int i = gid - c2;              // We[k][n], k=0..511, n=0..127
        int k = i >> 7, n = i & 127;
        if (k < 384) {
            ushort b = f2b(We_w[i]);
            if (k < 256)               // Bt12[(half*128+n)][k&127]
                Bt12[(((size_t)((k >> 7) << 7) + n) << 7) + (k & 127)] = b;
            else                       // W3t[n][k-256]
                W3t[((size_t)n << 7) + (k - 256)] = b;
        }
    } else if (gid < c4) {
        int i = gid - c3;              // Wn[k][n] -> Wnt[n][k], K=384
        int k = i >> 7, n = i & 127;
        Wnt[(size_t)n * 384 + k] = f2b(Wn_w[i]);
    }
}

// ---------------------------------------------------------------- u projection: up = u @ W4 + We_b (f32)
__global__ void uproj_kernel(const float* __restrict__ u, const float* __restrict__ We_w,
                             const float* __restrict__ We_b, float* __restrict__ upf)
{
    __shared__ float us[128];
    const int g = blockIdx.x;
    const int j = threadIdx.x;
    us[j] = u[g * D + j];
    __syncthreads();
    float s = We_b[j];
    for (int k = 0; k < 128; ++k) s += us[k] * We_w[(size_t)(384 + k) * D + j];
    upf[g * D + j] = s;
}

// ---------------------------------------------------------------- node projection GEMM:
// npf[n][0:128]   = node@W1 + up[batch[n]]   (up includes We_b)
// npf[n][128:256] = node@W2
// tile 128 rows x 256 cols, K=128. 4 waves (2M x 2N), each 64x128 (acc[4][8]).
// B columns permuted at staging so lane (l&15) holds 8 CONTIGUOUS true cols
// (l&15)*8..+7 within its half -> vectorized f32x4 epilogue stores/gathers.
__global__ __launch_bounds__(256) void nproj_gemm(
    const ushort* __restrict__ node_bf, const ushort* __restrict__ Bt12,
    const float* __restrict__ upf, const int* __restrict__ batch,
    float* __restrict__ npf, int N)
{
    __shared__ ushort As[128 * 32];   // 8 KB
    __shared__ ushort Bs[256 * 32];   // 16 KB
    __shared__ int rbs[128];

    const int tid = threadIdx.x;
    const int w = tid >> 6, l = tid & 63;
    const int n0 = blockIdx.x * 128;

    if (tid < 128) {
        int n = n0 + tid; if (n >= N) n = N - 1;
        rbs[tid] = batch[n];
    }

    f32x4 acc[4][8];
#pragma unroll
    for (int i = 0; i < 4; ++i)
#pragma unroll
        for (int j = 0; j < 8; ++j) acc[i][j] = (f32x4)0.0f;

    const int wm = (w >> 1) * 64, wn = (w & 1) * 128;
    const int srow = l >> 2;
    const int part = (l & 3) * 8;

    for (int c = 0; c < 4; ++c) {
        const int kl = c * 32;
#pragma unroll
        for (int t = 0; t < 2; ++t) {   // A: 8 segs of 16 rows
            const int s = w + t * 4;
            int n = n0 + s * 16 + srow; if (n >= N) n = N - 1;
            gl_lds16(node_bf + (size_t)n * D + kl + part, &As[s * 512]);
        }
#pragma unroll
        for (int t = 0; t < 4; ++t) {   // B: 16 segs, column-permuted within half
            const int s = w * 4 + t;
            const int br = s * 16 + srow;             // 0..255 tile row
            const int h = br >> 7, b7 = br & 127;
            const int n = (h << 7) | ((b7 & 15) << 3) | (b7 >> 4);
            gl_lds16(Bt12 + (size_t)n * 128 + kl + part, &Bs[s * 512]);
        }
        __syncthreads();

        bf16x8 af[4], bfr[8];
#pragma unroll
        for (int i = 0; i < 4; ++i)
            af[i] = *(const bf16x8*)&As[(wm + i * 16 + (l & 15)) * 32 + (l >> 4) * 8];
#pragma unroll
        for (int j = 0; j < 8; ++j)
            bfr[j] = *(const bf16x8*)&Bs[(wn + j * 16 + (l & 15)) * 32 + (l >> 4) * 8];
#pragma unroll
        for (int i = 0; i < 4; ++i)
#pragma unroll
            for (int j = 0; j < 8; ++j)
                acc[i][j] = __builtin_amdgcn_mfma_f32_16x16x32_bf16(af[i], bfr[j], acc[i][j], 0, 0, 0);
        __syncthreads();
    }

    // epilogue: lane holds true cols wn + (l&15)*8 .. +7 (contiguous)
    const int cc = l & 15;
    const int qr = (l >> 4) * 4;
#pragma unroll
    for (int i = 0; i < 4; ++i) {
#pragma unroll
        for (int r = 0; r < 4; ++r) {
            const int m = wm + i * 16 + qr + r;
            const int n = n0 + m;
            if (n < N) {
                float4 u0 = make_float4(0.f, 0.f, 0.f, 0.f);
                float4 u1 = make_float4(0.f, 0.f, 0.f, 0.f);
                if (wn == 0) {   // wave-uniform branch
                    const float* pu = upf + (size_t)rbs[m] * D + cc * 8;
                    u0 = *(const float4*)pu;
                    u1 = *(const float4*)(pu + 4);
                }
                float4 o0, o1;
                o0.x = acc[i][0][r] + u0.x; o0.y = acc[i][1][r] + u0.y;
                o0.z = acc[i][2][r] + u0.z; o0.w = acc[i][3][r] + u0.w;
                o1.x = acc[i][4][r] + u1.x; o1.y = acc[i][5][r] + u1.y;
                o1.z = acc[i][6][r] + u1.z; o1.w = acc[i][7][r] + u1.w;
                float* op = npf + (size_t)n * 256 + wn + cc * 8;
                *(float4*)op = o0;
                *(float4*)(op + 4) = o1;
            }
        }
    }
}

// ---------------------------------------------------------------- edge update GEMM (MFMA bf16), K=128
// e' = relu(e@W3 + np1'[src] + np2[dst])   (np1' includes u-proj + bias)
// tile 256 edges x 128 cols. 4 waves, each 64 rows x 128 cols (acc[4][8]).
// B columns permuted at staging -> lane holds 8 contiguous cols (vector epilogue).
__global__ __launch_bounds__(256, 2) void edge_gemm(
    ushort* __restrict__ edge_u,
    const float* __restrict__ npf,
    const int* __restrict__ src, const int* __restrict__ dst,
    const ushort* __restrict__ W3t, int E)
{
    __shared__ ushort As[256 * 32];   // 16 KB
    __shared__ ushort Bs[128 * 32];   // 8 KB
    __shared__ int rs[256], rd[256];

    const int tid = threadIdx.x;
    const int w = tid >> 6, l = tid & 63;
    const int e0 = blockIdx.x * 256;

    {
        int e = e0 + tid; if (e >= E) e = E - 1;
        rs[tid] = src[e]; rd[tid] = dst[e];
    }

    f32x4 acc[4][8];
#pragma unroll
    for (int i = 0; i < 4; ++i)
#pragma unroll
        for (int j = 0; j < 8; ++j) acc[i][j] = (f32x4)0.0f;

    const int wm = w * 64;             // wave's M offset
    const int srow = l >> 2;           // 0..15 within seg
    const int part = (l & 3) * 8;      // ushort offset within 64B row chunk

    __syncthreads();                   // rs/rd visible

    for (int c = 0; c < 4; ++c) {
        const int kl = c * 32;         // k offset within 128-ushort row

#pragma unroll
        for (int t = 0; t < 4; ++t) {  // A: 4 segs of 16 edge rows per wave (16 segs)
            const int s = w * 4 + t;
            int e = e0 + s * 16 + srow; if (e >= E) e = E - 1;
            gl_lds16(edge_u + (size_t)e * 256 + kl + part, &As[s * 512]);
        }
#pragma unroll
        for (int t = 0; t < 2; ++t) {  // B: 8 segs, column-permuted
            const int s = w + t * 4;
            const int br = s * 16 + srow;
            const int n = ((br & 15) << 3) | (br >> 4);
            gl_lds16(W3t + (size_t)n * 128 + kl + part, &Bs[s * 512]);
        }
        __syncthreads();               // drains vmcnt -> LDS ready

        bf16x8 af[4], bfr[8];
#pragma unroll
        for (int i = 0; i < 4; ++i)
            af[i] = *(const bf16x8*)&As[(wm + i * 16 + (l & 15)) * 32 + (l >> 4) * 8];
#pragma unroll
        for (int j = 0; j < 8; ++j)
            bfr[j] = *(const bf16x8*)&Bs[(j * 16 + (l & 15)) * 32 + (l >> 4) * 8];
#pragma unroll
        for (int i = 0; i < 4; ++i)
#pragma unroll
            for (int j = 0; j < 8; ++j)
                acc[i][j] = __builtin_amdgcn_mfma_f32_16x16x32_bf16(af[i], bfr[j], acc[i][j], 0, 0, 0);
        __syncthreads();               // compute done before next overwrite
    }

    // epilogue: lane holds true cols (l&15)*8..+7; vector gather + 16B store
    const int cc = l & 15;
    const int qr = (l >> 4) * 4;
#pragma unroll
    for (int i = 0; i < 4; ++i) {
#pragma unroll
        for (int r = 0; r < 4; ++r) {
            const int m = wm + i * 16 + qr + r;
            const int e = e0 + m;
            if (e < E) {
                const float* p1 = npf + (size_t)rs[m] * 256 + cc * 8;
                const float* p2 = npf + (size_t)rd[m] * 256 + 128 + cc * 8;
                float4 a0 = *(const float4*)p1;
                float4 a1 = *(const float4*)(p1 + 4);
                float4 b0 = *(const float4*)p2;
                float4 b1 = *(const float4*)(p2 + 4);
                ushort8 o;
                o[0] = f2b(fmaxf(acc[i][0][r] + a0.x + b0.x, 0.0f));
                o[1] = f2b(fmaxf(acc[i][1][r] + a0.y + b0.y, 0.0f));
                o[2] = f2b(fmaxf(acc[i][2][r] + a0.z + b0.z, 0.0f));
                o[3] = f2b(fmaxf(acc[i][3][r] + a0.w + b0.w, 0.0f));
                o[4] = f2b(fmaxf(acc[i][4][r] + a1.x + b1.x, 0.0f));
                o[5] = f2b(fmaxf(acc[i][5][r] + a1.y + b1.y, 0.0f));
                o[6] = f2b(fmaxf(acc[i][6][r] + a1.z + b1.z, 0.0f));
                o[7] = f2b(fmaxf(acc[i][7][r] + a1.w + b1.w, 0.0f));
                *(ushort8*)(edge_u + (size_t)e * 256 + cc * 8) = o;
            }
        }
    }
}

// ---------------------------------------------------------------- ebar gather (CSR, vectorized)
// 8 nodes/block, 32 lanes/node, ushort4 (4 cols) per lane.
__global__ void gather_ebar(const ushort* __restrict__ edge_u, const int* __restrict__ offs,
                            const int* __restrict__ csr, ushort* __restrict__ ebar_bf, int N)
{
    int n = blockIdx.x * 8 + (threadIdx.x >> 5);
    int q = threadIdx.x & 31;
    if (n >= N) return;
    int lo = offs[n], hi = offs[n + 1];
    float s0 = 0.0f, s1 = 0.0f, s2 = 0.0f, s3 = 0.0f;
    for (int j = lo; j < hi; ++j) {
        int e = csr[j];
        ushort4 v = *(const ushort4*)(edge_u + (size_t)e * 256 + q * 4);
        s0 += b2f(v.x); s1 += b2f(v.y); s2 += b2f(v.z); s3 += b2f(v.w);
    }
    float inv = 1.0f / (float)max(hi - lo, 1);
    ushort4 o; o.x = f2b(s0 * inv); o.y = f2b(s1 * inv); o.z = f2b(s2 * inv); o.w = f2b(s3 * inv);
    *(ushort4*)(ebar_bf + (size_t)n * D + q * 4) = o;
}

// ---------------------------------------------------------------- node update GEMM (MFMA bf16), K=384
__global__ __launch_bounds__(256) void node_gemm(
    ushort* __restrict__ node_bf, const ushort* __restrict__ ebar_bf,
    const ushort* __restrict__ u_bf, const int* __restrict__ batch,
    const ushort* __restrict__ Wt, const float* __restrict__ bias, int N)
{
    __shared__ ushort As[128 * 32];
    __shared__ ushort Bs[128 * 32];
    __shared__ int rb[128];

    const int tid = threadIdx.x;
    const int w = tid >> 6, l = tid & 63;
    const int n0 = blockIdx.x * 128;

    if (tid < 128) {
        int n = n0 + tid; if (n >= N) n = N - 1;
        rb[tid] = batch[n];
    }

    f32x4 acc[4][4];
#pragma unroll
    for (int i = 0; i < 4; ++i)
#pragma unroll
        for (int j = 0; j < 4; ++j) acc[i][j] = (f32x4)0.0f;

    const int wm = (w >> 1) * 64, wn = (w & 1) * 64;
    float bj4[4];
#pragma unroll
    for (int j = 0; j < 4; ++j) bj4[j] = bias[wn + j * 16 + (l & 15)];

    const int srow = l >> 2;
    const int part = (l & 3) * 8;

    __syncthreads();

    for (int c = 0; c < 12; ++c) {
        const int srcsel = c >> 2;
        const int kl = (c & 3) * 32;

#pragma unroll
        for (int t = 0; t < 2; ++t) {
            const int s = w + t * 4;
            const int row = s * 16 + srow;
            int n = n0 + row; if (n >= N) n = N - 1;
            const ushort* gp;
            if (srcsel == 0)      gp = node_bf + (size_t)n * D + kl + part;
            else if (srcsel == 1) gp = ebar_bf + (size_t)n * D + kl + part;
            else                  gp = u_bf + (size_t)rb[row] * D + kl + part;
            gl_lds16(gp, &As[s * 512]);
        }
#pragma unroll
        for (int t = 0; t < 2; ++t) {
            const int s = w + t * 4;
            const int n = s * 16 + srow;
            gl_lds16(Wt + (size_t)n * 384 + c * 32 + part, &Bs[s * 512]);
        }
        __syncthreads();

        bf16x8 af[4], bfr[4];
#pragma unroll
        for (int i = 0; i < 4; ++i)
            af[i] = *(const bf16x8*)&As[(wm + i * 16 + (l & 15)) * 32 + (l >> 4) * 8];
#pragma unroll
        for (int j = 0; j < 4; ++j)
            bfr[j] = *(const bf16x8*)&Bs[(wn + j * 16 + (l & 15)) * 32 + (l >> 4) * 8];
#pragma unroll
        for (int i = 0; i < 4; ++i)
#pragma unroll
            for (int j = 0; j < 4; ++j)
                acc[i][j] = __builtin_amdgcn_mfma_f32_16x16x32_bf16(af[i], bfr[j], acc[i][j], 0, 0, 0);
        __syncthreads();
    }

#pragma unroll
    for (int i = 0; i < 4; ++i) {
#pragma unroll
        for (int r = 0; r < 4; ++r) {
            const int m = wm + i * 16 + (l >> 4) * 4 + r;
            const int n = n0 + m;
            if (n < N) {
#pragma unroll
                for (int j = 0; j < 4; ++j) {
                    float v = fmaxf(acc[i][j][r] + bj4[j], 0.0f);
                    node_bf[(size_t)n * D + wn + j * 16 + (l & 15)] = f2b(v);
                }
            }
        }
    }
}

// ---------------------------------------------------------------- per-graph sums, phase 1
__global__ void reduce_partial(
    const ushort* __restrict__ node_bf, const ushort* __restrict__ ebar_bf,
    const int* __restrict__ batch,
    float* __restrict__ nsum, float* __restrict__ esum, int N)
{
    const int col = threadIdx.x & 127;
    const int half = threadIdx.x >> 7;
    const int r0 = blockIdx.x * 128;
    float sn = 0.0f, se = 0.0f;
    int cur = -1;
    for (int ri = half; ri < 128; ri += 2) {
        int r = r0 + ri;
        if (r >= N) break;
        int g = batch[r];
        if (g != cur) {
            if (cur >= 0) {
                atomicAdd(&nsum[cur * D + col], sn);
                atomicAdd(&esum[cur * D + col], se);
            }
            cur = g; sn = 0.0f; se = 0.0f;
        }
        sn += b2f(node_bf[(size_t)r * D + col]);
        se += b2f(ebar_bf[(size_t)r * D + col]);
    }
    if (cur >= 0) {
        atomicAdd(&nsum[cur * D + col], sn);
        atomicAdd(&esum[cur * D + col], se);
    }
}

// ---------------------------------------------------------------- phase 2 + global update fused
__global__ void finalize_global(
    float* __restrict__ nsum, float* __restrict__ esum,
    const int* __restrict__ batch,
    float* __restrict__ nmean, float* __restrict__ emean,
    float* __restrict__ u, ushort* __restrict__ u_bf,
    const float* __restrict__ W, const float* __restrict__ bias, int N)
{
    __shared__ float gin[384];
    __shared__ int cnt_s;
    const int g = blockIdx.x;
    const int j = threadIdx.x;   // 0..127
    if (j == 0) {
        int lo = lower_bound_i(batch, N, g);
        int hi = lower_bound_i(batch, N, g + 1);
        cnt_s = hi - lo;
    }
    __syncthreads();
    float inv = 1.0f / (float)max(cnt_s, 1);
    float nm = nsum[g * D + j] * inv;
    float em = esum[g * D + j] * inv;
    nmean[g * D + j] = nm;
    emean[g * D + j] = em;
    nsum[g * D + j] = 0.0f;
    esum[g * D + j] = 0.0f;
    gin[j] = nm; gin[128 + j] = em; gin[256 + j] = u[g * D + j];
    __syncthreads();
    float s = bias[j];
    for (int k = 0; k < 384; ++k) s += gin[k] * W[(size_t)k * D + j];
    float v = fmaxf(s, 0.0f);
    u[g * D + j] = v;
    u_bf[g * D + j] = f2b(v);
}

// ---------------------------------------------------------------- readout
__global__ void out_kernel(
    const float* __restrict__ nmean, const float* __restrict__ emean,
    const float* __restrict__ u, const int* __restrict__ batch,
    const float* __restrict__ lw, const float* __restrict__ lb,
    float* __restrict__ out, int N, int NC)
{
    __shared__ float pin[384];
    __shared__ int cntg;
    const int g = blockIdx.x;
    const int t = threadIdx.x;   // 0..383
    if (t == 0) {
        int lo = lower_bound_i(batch, N, g);
        int hi = lower_bound_i(batch, N, g + 1);
        cntg = hi - lo;
    }
    __syncthreads();
    if (t < 128)       pin[t] = nmean[g * D + t];
    else if (t < 256)  pin[t] = emean[g * D + (t - 128)];
    else               pin[t] = (cntg > 0) ? u[g * D + (t - 256)] : 0.0f;
    __syncthreads();
    int c = t >> 5, wv = t & 31;
    if (c < NC) {
        float s = 0.0f;
        for (int k = wv; k < 384; k += 32) s += pin[k] * lw[(size_t)k * NC + c];
#pragma unroll
        for (int off = 16; off > 0; off >>= 1) s += __shfl_down(s, off, 32);
        if (wv == 0) out[g * NC + c] = s + lb[c];
    }
}

// ---------------------------------------------------------------- driver
extern "C" void kernel_launch(void* const* d_in, const int* in_sizes, int n_in,
                              void* d_out, int out_size, void* d_ws, size_t ws_size,
                              hipStream_t stream) {
    float* node = (float*)d_in[0];
    float* edge = (float*)d_in[1];
    float* u    = (float*)d_in[2];
    const int* eidx  = (const int*)d_in[3];
    const int* batch = (const int*)d_in[4];
    const float* We_w = (const float*)d_in[5];
    const float* We_b = (const float*)d_in[6];
    const float* Wn_w = (const float*)d_in[7];
    const float* Wn_b = (const float*)d_in[8];
    const float* Wg_w = (const float*)d_in[9];
    const float* Wg_b = (const float*)d_in[10];
    const float* lin_w = (const float*)d_in[11];
    const float* lin_b = (const float*)d_in[12];

    const int N = in_sizes[0] / D;        // 50000
    const int E = in_sizes[3] / 2;        // 600000
    const int G = in_sizes[2] / D;        // 64
    const int NC = out_size / G;          // 10
    const int* src = eidx;
    const int* dst = eidx + E;

    // workspace carve-up (256B-aligned chunks); cnt..esum contiguous for single memset
    char* p = (char*)d_ws;
    auto carve = [&](size_t bytes) { void* r = p; p += (bytes + 255) & ~(size_t)255; return r; };
    int*    cnt     = (int*)carve((size_t)N * 4);
    int*    fill    = (int*)carve((size_t)N * 4);
    float*  nsum    = (float*)carve((size_t)G * D * 4);
    float*  esum    = (float*)carve((size_t)G * D * 4);
    size_t  zspan   = (size_t)(p - (char*)cnt);
    int*    offs    = (int*)carve((size_t)(N + 1) * 4);
    int*    csr     = (int*)carve((size_t)E * 4);
    ushort* node_bf = (ushort*)carve((size_t)N * D * 2);
    ushort* ebar_bf = (ushort*)carve((size_t)N * D * 2);
    ushort* u_bf    = (ushort*)carve((size_t)G * D * 2);
    ushort* Bt12    = (ushort*)carve((size_t)256 * 128 * 2);
    ushort* W3t     = (ushort*)carve((size_t)128 * 128 * 2);
    ushort* Wnt     = (ushort*)carve((size_t)384 * D * 2);
    float*  nmean   = (float*)carve((size_t)G * D * 4);
    float*  emean   = (float*)carve((size_t)G * D * 4);
    float*  upf     = (float*)carve((size_t)G * D * 4);
    float*  npf     = (float*)carve((size_t)N * 256 * 4);

    ushort* edge_u = (ushort*)edge;  // bf16-in-place, row stride 256 ushorts

    hipMemsetAsync(cnt, 0, zspan, stream);   // cnt, fill, nsum, esum

    // CSR build (dst fixed per call)
    count_kernel<<<(E + 255) / 256, 256, 0, stream>>>(dst, cnt, E);
    scan_kernel<<<1, 1024, 0, stream>>>(cnt, offs, N);
    scatter_kernel<<<(E + 255) / 256, 256, 0, stream>>>(dst, offs, fill, csr, E);

    // fused conversions / transposes
    const int prep_units = E * 32 + N * D / 4 + G * D / 4 + 512 * D + 384 * D;
    prep_kernel<<<(prep_units + 255) / 256, 256, 0, stream>>>(
        edge, node, node_bf, u, u_bf, We_w, Bt12, W3t, Wn_w, Wnt, N, G, E);

    const int edge_blocks = (E + 255) / 256;
    const int node_blocks = (N + 127) / 128;
    const int proj_blocks = (N + 127) / 128;
    const int red_blocks  = (N + 127) / 128;

    for (int pass = 0; pass < 3; ++pass) {
        uproj_kernel<<<G, 128, 0, stream>>>(u, We_w, We_b, upf);
        nproj_gemm<<<proj_blocks, 256, 0, stream>>>(node_bf, Bt12, upf, batch, npf, N);
        edge_gemm<<<edge_blocks, 256, 0, stream>>>(edge_u, npf, src, dst, W3t, E);
        gather_ebar<<<(N + 7) / 8, 256, 0, stream>>>(edge_u, offs, csr, ebar_bf, N);
        node_gemm<<<node_blocks, 256, 0, stream>>>(node_bf, ebar_bf, u_bf, batch,
                                                   Wnt, Wn_b, N);
        reduce_partial<<<red_blocks, 256, 0, stream>>>(node_bf, ebar_bf, batch, nsum, esum, N);
        finalize_global<<<G, 128, 0, stream>>>(nsum, esum, batch, nmean, emean,
                                               u, u_bf, Wg_w, Wg_b, N);
    }
    out_kernel<<<G, 384, 0, stream>>>(nmean, emean, u, batch, lin_w, lin_b,
                                      (float*)d_out, N, NC);
}

// Round 4
// 1204.915 us; speedup vs baseline: 1.1043x; 1.1028x over previous
//
#include <hip/hip_runtime.h>
#include <math.h>

#define D 128

typedef short bf16x8 __attribute__((ext_vector_type(8)));
typedef float f32x4 __attribute__((ext_vector_type(4)));
typedef ushort ushort8 __attribute__((ext_vector_type(8)));

// ---------------------------------------------------------------- bf16 helpers (RNE)
__device__ __forceinline__ ushort f2b(float f) {
    union { float f; unsigned u; } v; v.f = f;
    unsigned r = v.u + 0x7FFFu + ((v.u >> 16) & 1u);
    return (ushort)(r >> 16);
}
__device__ __forceinline__ float b2f(ushort b) {
    union { unsigned u; float f; } v; v.u = ((unsigned)b) << 16;
    return v.f;
}
// async global->LDS, 16B per lane; LDS dest = wave-uniform base + lane*16
__device__ __forceinline__ void gl_lds16(const void* g, void* l) {
    __builtin_amdgcn_global_load_lds(
        (const __attribute__((address_space(1))) void*)g,
        (__attribute__((address_space(3))) void*)l, 16, 0, 0);
}
__device__ __forceinline__ int lower_bound_i(const int* __restrict__ a, int n, int v) {
    int lo = 0, hi = n;
    while (lo < hi) { int m = (lo + hi) >> 1; if (a[m] < v) lo = m + 1; else hi = m; }
    return lo;
}

// ---------------------------------------------------------------- CSR build (dst fixed per call)
__global__ void count_kernel(const int* __restrict__ dst, int* __restrict__ cnt, int E) {
    int e = blockIdx.x * blockDim.x + threadIdx.x;
    if (e < E) atomicAdd(&cnt[dst[e]], 1);
}

__global__ void scan_kernel(const int* __restrict__ cnt, int* __restrict__ offs, int N) {
    __shared__ int part[1024];
    const int t = threadIdx.x;
    const int chunk = (N + 1023) >> 10;
    int lo = t * chunk; if (lo > N) lo = N;
    int hi = lo + chunk; if (hi > N) hi = N;
    int s = 0;
    for (int i = lo; i < hi; ++i) s += cnt[i];
    part[t] = s;
    __syncthreads();
    if (t == 0) {
        int a = 0;
        for (int i = 0; i < 1024; ++i) { int v = part[i]; part[i] = a; a += v; }
        offs[N] = a;
    }
    __syncthreads();
    int a = part[t];
    for (int i = lo; i < hi; ++i) { offs[i] = a; a += cnt[i]; }
}

// scatter + build permuted index arrays: csr[p]=orig edge, srcp[p]=src, dstp[p]=dst
__global__ void scatter_kernel(const int* __restrict__ dst, const int* __restrict__ src,
                               const int* __restrict__ offs,
                               int* __restrict__ fill, int* __restrict__ csr,
                               int* __restrict__ srcp, int* __restrict__ dstp, int E) {
    int e = blockIdx.x * blockDim.x + threadIdx.x;
    if (e < E) {
        int d = dst[e];
        int p = offs[d] + atomicAdd(&fill[d], 1);
        csr[p] = e;
        srcp[p] = src[e];
        dstp[p] = d;
    }
}

// ---------------------------------------------------------------- fused prep:
// [0,c0)  edge fp32->bf16 in-place (row e bf16 in LOWER 256B of its 512B slot;
//         UPPER 256B of each slot is reused later as dst-sorted e' storage)
// [c0,c1) node f2b, [c1,c2) u f2b,
// [c2,c3) We split-transpose -> Bt12 (W1|W2, 256x128) + W3t (128x128),
// [c3,c4) Wn transpose
__global__ void prep_kernel(
    float* __restrict__ edge,
    const float* __restrict__ node, ushort* __restrict__ node_bf,
    const float* __restrict__ u, ushort* __restrict__ u_bf,
    const float* __restrict__ We_w, ushort* __restrict__ Bt12, ushort* __restrict__ W3t,
    const float* __restrict__ Wn_w, ushort* __restrict__ Wnt,
    int N, int G, int E)
{
    const int gid = blockIdx.x * 256 + threadIdx.x;
    const int c0 = E * 32;
    const int c1 = c0 + N * D / 4;
    const int c2 = c1 + G * D / 4;
    const int c3 = c2 + 512 * D;
    const int c4 = c3 + 384 * D;
    if (gid < c0) {
        int row = gid >> 5, q = gid & 31;
        float4 v = *(const float4*)(edge + (size_t)row * D + q * 4);
        ushort4 o; o.x = f2b(v.x); o.y = f2b(v.y); o.z = f2b(v.z); o.w = f2b(v.w);
        *(ushort4*)((ushort*)edge + (size_t)row * 256 + q * 4) = o;
    } else if (gid < c1) {
        int i = (gid - c0) * 4;
        float4 v = *(const float4*)(node + i);
        ushort4 o; o.x = f2b(v.x); o.y = f2b(v.y); o.z = f2b(v.z); o.w = f2b(v.w);
        *(ushort4*)(node_bf + i) = o;
    } else if (gid < c2) {
        int i = (gid - c1) * 4;
        float4 v = *(const float4*)(u + i);
        ushort4 o; o.x = f2b(v.x); o.y = f2b(v.y); o.z = f2b(v.z); o.w = f2b(v.w);
        *(ushort4*)(u_bf + i) = o;
    } else if (gid < c3) {
        int i = gid - c2;              // We[k][n], k=0..511, n=0..127
        int k = i >> 7, n = i & 127;
        if (k < 384) {
            ushort b = f2b(We_w[i]);
            if (k < 256)               // Bt12[(half*128+n)][k&127]
                Bt12[(((size_t)((k >> 7) << 7) + n) << 7) + (k & 127)] = b;
            else                       // W3t[n][k-256]
                W3t[((size_t)n << 7) + (k - 256)] = b;
        }
    } else if (gid < c4) {
        int i = gid - c3;              // Wn[k][n] -> Wnt[n][k], K=384
        int k = i >> 7, n = i & 127;
        Wnt[(size_t)n * 384 + k] = f2b(Wn_w[i]);
    }
}

// ---------------------------------------------------------------- u projection: up = u @ W4 + We_b (f32)
__global__ void uproj_kernel(const float* __restrict__ u, const float* __restrict__ We_w,
                             const float* __restrict__ We_b, float* __restrict__ upf)
{
    __shared__ float us[128];
    const int g = blockIdx.x;
    const int j = threadIdx.x;
    us[j] = u[g * D + j];
    __syncthreads();
    float s = We_b[j];
    for (int k = 0; k < 128; ++k) s += us[k] * We_w[(size_t)(384 + k) * D + j];
    upf[g * D + j] = s;
}

// ---------------------------------------------------------------- node projection GEMM:
// npb[n][0:128]  = bf16(node@W1 + up[batch[n]])   (up includes We_b)  <- random-gathered later
// npf2[n][0:128] = f32 (node@W2)                                      <- dst-local, cached
// tile 128 rows x 256 cols, K=128. 4 waves (2M x 2N), each 64x128 (acc[4][8]).
// B columns permuted at staging so lane (l&15) holds 8 CONTIGUOUS true cols.
__global__ __launch_bounds__(256) void nproj_gemm(
    const ushort* __restrict__ node_bf, const ushort* __restrict__ Bt12,
    const float* __restrict__ upf, const int* __restrict__ batch,
    ushort* __restrict__ npb, float* __restrict__ npf2, int N)
{
    __shared__ ushort As[128 * 32];   // 8 KB
    __shared__ ushort Bs[256 * 32];   // 16 KB
    __shared__ int rbs[128];

    const int tid = threadIdx.x;
    const int w = tid >> 6, l = tid & 63;
    const int n0 = blockIdx.x * 128;

    if (tid < 128) {
        int n = n0 + tid; if (n >= N) n = N - 1;
        rbs[tid] = batch[n];
    }

    f32x4 acc[4][8];
#pragma unroll
    for (int i = 0; i < 4; ++i)
#pragma unroll
        for (int j = 0; j < 8; ++j) acc[i][j] = (f32x4)0.0f;

    const int wm = (w >> 1) * 64, wn = (w & 1) * 128;
    const int srow = l >> 2;
    const int part = (l & 3) * 8;

    for (int c = 0; c < 4; ++c) {
        const int kl = c * 32;
#pragma unroll
        for (int t = 0; t < 2; ++t) {   // A: 8 segs of 16 rows
            const int s = w + t * 4;
            int n = n0 + s * 16 + srow; if (n >= N) n = N - 1;
            gl_lds16(node_bf + (size_t)n * D + kl + part, &As[s * 512]);
        }
#pragma unroll
        for (int t = 0; t < 4; ++t) {   // B: 16 segs, column-permuted within half
            const int s = w * 4 + t;
            const int br = s * 16 + srow;             // 0..255 tile row
            const int h = br >> 7, b7 = br & 127;
            const int n = (h << 7) | ((b7 & 15) << 3) | (b7 >> 4);
            gl_lds16(Bt12 + (size_t)n * 128 + kl + part, &Bs[s * 512]);
        }
        __syncthreads();

        bf16x8 af[4], bfr[8];
#pragma unroll
        for (int i = 0; i < 4; ++i)
            af[i] = *(const bf16x8*)&As[(wm + i * 16 + (l & 15)) * 32 + (l >> 4) * 8];
#pragma unroll
        for (int j = 0; j < 8; ++j)
            bfr[j] = *(const bf16x8*)&Bs[(wn + j * 16 + (l & 15)) * 32 + (l >> 4) * 8];
#pragma unroll
        for (int i = 0; i < 4; ++i)
#pragma unroll
            for (int j = 0; j < 8; ++j)
                acc[i][j] = __builtin_amdgcn_mfma_f32_16x16x32_bf16(af[i], bfr[j], acc[i][j], 0, 0, 0);
        __syncthreads();
    }

    // epilogue: lane holds true cols (l&15)*8..+7 (contiguous) within its half
    const int cc = l & 15;
    const int qr = (l >> 4) * 4;
#pragma unroll
    for (int i = 0; i < 4; ++i) {
#pragma unroll
        for (int r = 0; r < 4; ++r) {
            const int m = wm + i * 16 + qr + r;
            const int n = n0 + m;
            if (n < N) {
                if (wn == 0) {   // np1' half: + u-proj, bf16 store
                    const float* pu = upf + (size_t)rbs[m] * D + cc * 8;
                    float4 u0 = *(const float4*)pu;
                    float4 u1 = *(const float4*)(pu + 4);
                    ushort8 o;
                    o[0] = f2b(acc[i][0][r] + u0.x);
                    o[1] = f2b(acc[i][1][r] + u0.y);
                    o[2] = f2b(acc[i][2][r] + u0.z);
                    o[3] = f2b(acc[i][3][r] + u0.w);
                    o[4] = f2b(acc[i][4][r] + u1.x);
                    o[5] = f2b(acc[i][5][r] + u1.y);
                    o[6] = f2b(acc[i][6][r] + u1.z);
                    o[7] = f2b(acc[i][7][r] + u1.w);
                    *(ushort8*)(npb + (size_t)n * 128 + cc * 8) = o;
                } else {         // np2 half: f32 store
                    float4 o0, o1;
                    o0.x = acc[i][0][r]; o0.y = acc[i][1][r];
                    o0.z = acc[i][2][r]; o0.w = acc[i][3][r];
                    o1.x = acc[i][4][r]; o1.y = acc[i][5][r];
                    o1.z = acc[i][6][r]; o1.w = acc[i][7][r];
                    float* op = npf2 + (size_t)n * 128 + cc * 8;
                    *(float4*)op = o0;
                    *(float4*)(op + 4) = o1;
                }
            }
        }
    }
}

// ---------------------------------------------------------------- edge update GEMM (MFMA bf16), K=128
// Edge slot layout (512B stride in the input edge buffer):
//   lower 256B = original bf16 edge row (prep output; pass-0 A source via csr)
//   upper 256B = dst-sorted e' (all passes write here; passes>=1 read sequentially)
// rc[] holds HALF-SLOT index: pass0 -> csr[e]*2 (lower half), else e*2+1 (upper half).
// e'[p] = relu(e[p]@W3 + np1'[srcp[p]] + np2[dstp[p]])
__global__ __launch_bounds__(256, 2) void edge_gemm(
    ushort* __restrict__ edge_buf,
    const int* __restrict__ csr,
    const int* __restrict__ srcp, const int* __restrict__ dstp,
    const ushort* __restrict__ npb, const float* __restrict__ npf2,
    const ushort* __restrict__ W3t, int E, int pass0)
{
    __shared__ ushort As[256 * 32];   // 16 KB
    __shared__ ushort Bs[128 * 32];   // 8 KB
    __shared__ int rs[256], rd[256], rc[256];

    const int tid = threadIdx.x;
    const int w = tid >> 6, l = tid & 63;
    const int e0 = blockIdx.x * 256;

    {
        int e = e0 + tid; if (e >= E) e = E - 1;
        rs[tid] = srcp[e]; rd[tid] = dstp[e];
        rc[tid] = pass0 ? (csr[e] * 2) : (e * 2 + 1);
    }

    f32x4 acc[4][8];
#pragma unroll
    for (int i = 0; i < 4; ++i)
#pragma unroll
        for (int j = 0; j < 8; ++j) acc[i][j] = (f32x4)0.0f;

    const int wm = w * 64;             // wave's M offset
    const int srow = l >> 2;           // 0..15 within seg
    const int part = (l & 3) * 8;      // ushort offset within 64B row chunk

    __syncthreads();                   // rs/rd/rc visible

    for (int c = 0; c < 4; ++c) {
        const int kl = c * 32;         // k offset within 128-ushort row

#pragma unroll
        for (int t = 0; t < 4; ++t) {  // A: 4 segs of 16 edge rows per wave (16 segs)
            const int s = w * 4 + t;
            const int row = s * 16 + srow;
            gl_lds16(edge_buf + (size_t)rc[row] * 128 + kl + part, &As[s * 512]);
        }
#pragma unroll
        for (int t = 0; t < 2; ++t) {  // B: 8 segs, column-permuted
            const int s = w + t * 4;
            const int br = s * 16 + srow;
            const int n = ((br & 15) << 3) | (br >> 4);
            gl_lds16(W3t + (size_t)n * 128 + kl + part, &Bs[s * 512]);
        }
        __syncthreads();               // drains vmcnt -> LDS ready

        bf16x8 af[4], bfr[8];
#pragma unroll
        for (int i = 0; i < 4; ++i)
            af[i] = *(const bf16x8*)&As[(wm + i * 16 + (l & 15)) * 32 + (l >> 4) * 8];
#pragma unroll
        for (int j = 0; j < 8; ++j)
            bfr[j] = *(const bf16x8*)&Bs[(j * 16 + (l & 15)) * 32 + (l >> 4) * 8];
#pragma unroll
        for (int i = 0; i < 4; ++i)
#pragma unroll
            for (int j = 0; j < 8; ++j)
                acc[i][j] = __builtin_amdgcn_mfma_f32_16x16x32_bf16(af[i], bfr[j], acc[i][j], 0, 0, 0);
        __syncthreads();               // compute done before next overwrite
    }

    // epilogue: lane holds true cols (l&15)*8..+7; 16-lane groups read full
    // coalesced 256B np rows; dst-sorted => np2 rows mostly L1/L2-hit.
    const int cc = l & 15;
    const int qr = (l >> 4) * 4;
#pragma unroll
    for (int i = 0; i < 4; ++i) {
#pragma unroll
        for (int r = 0; r < 4; ++r) {
            const int m = wm + i * 16 + qr + r;
            const int e = e0 + m;
            if (e < E) {
                ushort8 p1 = *(const ushort8*)(npb + (size_t)rs[m] * 128 + cc * 8);
                const float* p2 = npf2 + (size_t)rd[m] * 128 + cc * 8;
                float4 b0 = *(const float4*)p2;
                float4 b1 = *(const float4*)(p2 + 4);
                ushort8 o;
                o[0] = f2b(fmaxf(acc[i][0][r] + b2f(p1[0]) + b0.x, 0.0f));
                o[1] = f2b(fmaxf(acc[i][1][r] + b2f(p1[1]) + b0.y, 0.0f));
                o[2] = f2b(fmaxf(acc[i][2][r] + b2f(p1[2]) + b0.z, 0.0f));
                o[3] = f2b(fmaxf(acc[i][3][r] + b2f(p1[3]) + b0.w, 0.0f));
                o[4] = f2b(fmaxf(acc[i][4][r] + b2f(p1[4]) + b1.x, 0.0f));
                o[5] = f2b(fmaxf(acc[i][5][r] + b2f(p1[5]) + b1.y, 0.0f));
                o[6] = f2b(fmaxf(acc[i][6][r] + b2f(p1[6]) + b1.z, 0.0f));
                o[7] = f2b(fmaxf(acc[i][7][r] + b2f(p1[7]) + b1.w, 0.0f));
                *(ushort8*)(edge_buf + (size_t)e * 256 + 128 + cc * 8) = o;
            }
        }
    }
}

// ---------------------------------------------------------------- ebar (dst-sorted upper halves: sequential)
// 8 nodes/block, 32 lanes/node, ushort4 (4 cols) per lane; rows offs[n]..offs[n+1] contiguous.
__global__ void gather_ebar(const ushort* __restrict__ edge_buf, const int* __restrict__ offs,
                            ushort* __restrict__ ebar_bf, int N)
{
    int n = blockIdx.x * 8 + (threadIdx.x >> 5);
    int q = threadIdx.x & 31;
    if (n >= N) return;
    int lo = offs[n], hi = offs[n + 1];
    float s0 = 0.0f, s1 = 0.0f, s2 = 0.0f, s3 = 0.0f;
    for (int j = lo; j < hi; ++j) {
        ushort4 v = *(const ushort4*)(edge_buf + (size_t)j * 256 + 128 + q * 4);
        s0 += b2f(v.x); s1 += b2f(v.y); s2 += b2f(v.z); s3 += b2f(v.w);
    }
    float inv = 1.0f / (float)max(hi - lo, 1);
    ushort4 o; o.x = f2b(s0 * inv); o.y = f2b(s1 * inv); o.z = f2b(s2 * inv); o.w = f2b(s3 * inv);
    *(ushort4*)(ebar_bf + (size_t)n * D + q * 4) = o;
}

// ---------------------------------------------------------------- node update GEMM (MFMA bf16), K=384
__global__ __launch_bounds__(256) void node_gemm(
    ushort* __restrict__ node_bf, const ushort* __restrict__ ebar_bf,
    const ushort* __restrict__ u_bf, const int* __restrict__ batch,
    const ushort* __restrict__ Wt, const float* __restrict__ bias, int N)
{
    __shared__ ushort As[128 * 32];
    __shared__ ushort Bs[128 * 32];
    __shared__ int rb[128];

    const int tid = threadIdx.x;
    const int w = tid >> 6, l = tid & 63;
    const int n0 = blockIdx.x * 128;

    if (tid < 128) {
        int n = n0 + tid; if (n >= N) n = N - 1;
        rb[tid] = batch[n];
    }

    f32x4 acc[4][4];
#pragma unroll
    for (int i = 0; i < 4; ++i)
#pragma unroll
        for (int j = 0; j < 4; ++j) acc[i][j] = (f32x4)0.0f;

    const int wm = (w >> 1) * 64, wn = (w & 1) * 64;
    float bj4[4];
#pragma unroll
    for (int j = 0; j < 4; ++j) bj4[j] = bias[wn + j * 16 + (l & 15)];

    const int srow = l >> 2;
    const int part = (l & 3) * 8;

    __syncthreads();

    for (int c = 0; c < 12; ++c) {
        const int srcsel = c >> 2;
        const int kl = (c & 3) * 32;

#pragma unroll
        for (int t = 0; t < 2; ++t) {
            const int s = w + t * 4;
            const int row = s * 16 + srow;
            int n = n0 + row; if (n >= N) n = N - 1;
            const ushort* gp;
            if (srcsel == 0)      gp = node_bf + (size_t)n * D + kl + part;
            else if (srcsel == 1) gp = ebar_bf + (size_t)n * D + kl + part;
            else                  gp = u_bf + (size_t)rb[row] * D + kl + part;
            gl_lds16(gp, &As[s * 512]);
        }
#pragma unroll
        for (int t = 0; t < 2; ++t) {
            const int s = w + t * 4;
            const int n = s * 16 + srow;
            gl_lds16(Wt + (size_t)n * 384 + c * 32 + part, &Bs[s * 512]);
        }
        __syncthreads();

        bf16x8 af[4], bfr[4];
#pragma unroll
        for (int i = 0; i < 4; ++i)
            af[i] = *(const bf16x8*)&As[(wm + i * 16 + (l & 15)) * 32 + (l >> 4) * 8];
#pragma unroll
        for (int j = 0; j < 4; ++j)
            bfr[j] = *(const bf16x8*)&Bs[(wn + j * 16 + (l & 15)) * 32 + (l >> 4) * 8];
#pragma unroll
        for (int i = 0; i < 4; ++i)
#pragma unroll
            for (int j = 0; j < 4; ++j)
                acc[i][j] = __builtin_amdgcn_mfma_f32_16x16x32_bf16(af[i], bfr[j], acc[i][j], 0, 0, 0);
        __syncthreads();
    }

#pragma unroll
    for (int i = 0; i < 4; ++i) {
#pragma unroll
        for (int r = 0; r < 4; ++r) {
            const int m = wm + i * 16 + (l >> 4) * 4 + r;
            const int n = n0 + m;
            if (n < N) {
#pragma unroll
                for (int j = 0; j < 4; ++j) {
                    float v = fmaxf(acc[i][j][r] + bj4[j], 0.0f);
                    node_bf[(size_t)n * D + wn + j * 16 + (l & 15)] = f2b(v);
                }
            }
        }
    }
}

// ---------------------------------------------------------------- per-graph sums, phase 1
__global__ void reduce_partial(
    const ushort* __restrict__ node_bf, const ushort* __restrict__ ebar_bf,
    const int* __restrict__ batch,
    float* __restrict__ nsum, float* __restrict__ esum, int N)
{
    const int col = threadIdx.x & 127;
    const int half = threadIdx.x >> 7;
    const int r0 = blockIdx.x * 128;
    float sn = 0.0f, se = 0.0f;
    int cur = -1;
    for (int ri = half; ri < 128; ri += 2) {
        int r = r0 + ri;
        if (r >= N) break;
        int g = batch[r];
        if (g != cur) {
            if (cur >= 0) {
                atomicAdd(&nsum[cur * D + col], sn);
                atomicAdd(&esum[cur * D + col], se);
            }
            cur = g; sn = 0.0f; se = 0.0f;
        }
        sn += b2f(node_bf[(size_t)r * D + col]);
        se += b2f(ebar_bf[(size_t)r * D + col]);
    }
    if (cur >= 0) {
        atomicAdd(&nsum[cur * D + col], sn);
        atomicAdd(&esum[cur * D + col], se);
    }
}

// ---------------------------------------------------------------- phase 2 + global update fused
__global__ void finalize_global(
    float* __restrict__ nsum, float* __restrict__ esum,
    const int* __restrict__ batch,
    float* __restrict__ nmean, float* __restrict__ emean,
    float* __restrict__ u, ushort* __restrict__ u_bf,
    const float* __restrict__ W, const float* __restrict__ bias, int N)
{
    __shared__ float gin[384];
    __shared__ int cnt_s;
    const int g = blockIdx.x;
    const int j = threadIdx.x;   // 0..127
    if (j == 0) {
        int lo = lower_bound_i(batch, N, g);
        int hi = lower_bound_i(batch, N, g + 1);
        cnt_s = hi - lo;
    }
    __syncthreads();
    float inv = 1.0f / (float)max(cnt_s, 1);
    float nm = nsum[g * D + j] * inv;
    float em = esum[g * D + j] * inv;
    nmean[g * D + j] = nm;
    emean[g * D + j] = em;
    nsum[g * D + j] = 0.0f;
    esum[g * D + j] = 0.0f;
    gin[j] = nm; gin[128 + j] = em; gin[256 + j] = u[g * D + j];
    __syncthreads();
    float s = bias[j];
    for (int k = 0; k < 384; ++k) s += gin[k] * W[(size_t)k * D + j];
    float v = fmaxf(s, 0.0f);
    u[g * D + j] = v;
    u_bf[g * D + j] = f2b(v);
}

// ---------------------------------------------------------------- readout
__global__ void out_kernel(
    const float* __restrict__ nmean, const float* __restrict__ emean,
    const float* __restrict__ u, const int* __restrict__ batch,
    const float* __restrict__ lw, const float* __restrict__ lb,
    float* __restrict__ out, int N, int NC)
{
    __shared__ float pin[384];
    __shared__ int cntg;
    const int g = blockIdx.x;
    const int t = threadIdx.x;   // 0..383
    if (t == 0) {
        int lo = lower_bound_i(batch, N, g);
        int hi = lower_bound_i(batch, N, g + 1);
        cntg = hi - lo;
    }
    __syncthreads();
    if (t < 128)       pin[t] = nmean[g * D + t];
    else if (t < 256)  pin[t] = emean[g * D + (t - 128)];
    else               pin[t] = (cntg > 0) ? u[g * D + (t - 256)] : 0.0f;
    __syncthreads();
    int c = t >> 5, wv = t & 31;
    if (c < NC) {
        float s = 0.0f;
        for (int k = wv; k < 384; k += 32) s += pin[k] * lw[(size_t)k * NC + c];
#pragma unroll
        for (int off = 16; off > 0; off >>= 1) s += __shfl_down(s, off, 32);
        if (wv == 0) out[g * NC + c] = s + lb[c];
    }
}

// ---------------------------------------------------------------- driver
extern "C" void kernel_launch(void* const* d_in, const int* in_sizes, int n_in,
                              void* d_out, int out_size, void* d_ws, size_t ws_size,
                              hipStream_t stream) {
    float* node = (float*)d_in[0];
    float* edge = (float*)d_in[1];
    float* u    = (float*)d_in[2];
    const int* eidx  = (const int*)d_in[3];
    const int* batch = (const int*)d_in[4];
    const float* We_w = (const float*)d_in[5];
    const float* We_b = (const float*)d_in[6];
    const float* Wn_w = (const float*)d_in[7];
    const float* Wn_b = (const float*)d_in[8];
    const float* Wg_w = (const float*)d_in[9];
    const float* Wg_b = (const float*)d_in[10];
    const float* lin_w = (const float*)d_in[11];
    const float* lin_b = (const float*)d_in[12];

    const int N = in_sizes[0] / D;        // 50000
    const int E = in_sizes[3] / 2;        // 600000
    const int G = in_sizes[2] / D;        // 64
    const int NC = out_size / G;          // 10
    const int* src = eidx;
    const int* dst = eidx + E;

    // workspace carve-up (256B-aligned chunks); cnt..esum contiguous for single memset
    // total ~72 MB (sorted e' lives in the upper halves of the input edge slots)
    char* p = (char*)d_ws;
    auto carve = [&](size_t bytes) { void* r = p; p += (bytes + 255) & ~(size_t)255; return r; };
    int*    cnt     = (int*)carve((size_t)N * 4);
    int*    fill    = (int*)carve((size_t)N * 4);
    float*  nsum    = (float*)carve((size_t)G * D * 4);
    float*  esum    = (float*)carve((size_t)G * D * 4);
    size_t  zspan   = (size_t)(p - (char*)cnt);
    int*    offs    = (int*)carve((size_t)(N + 1) * 4);
    int*    csr     = (int*)carve((size_t)E * 4);
    int*    srcp    = (int*)carve((size_t)E * 4);
    int*    dstp    = (int*)carve((size_t)E * 4);
    ushort* node_bf = (ushort*)carve((size_t)N * D * 2);
    ushort* ebar_bf = (ushort*)carve((size_t)N * D * 2);
    ushort* u_bf    = (ushort*)carve((size_t)G * D * 2);
    ushort* Bt12    = (ushort*)carve((size_t)256 * 128 * 2);
    ushort* W3t     = (ushort*)carve((size_t)128 * 128 * 2);
    ushort* Wnt     = (ushort*)carve((size_t)384 * D * 2);
    float*  nmean   = (float*)carve((size_t)G * D * 4);
    float*  emean   = (float*)carve((size_t)G * D * 4);
    float*  upf     = (float*)carve((size_t)G * D * 4);
    ushort* npb     = (ushort*)carve((size_t)N * 128 * 2);
    float*  npf2    = (float*)carve((size_t)N * 128 * 4);

    ushort* edge_bf = (ushort*)edge;  // 512B slots: lower half orig bf16, upper half sorted e'

    hipMemsetAsync(cnt, 0, zspan, stream);   // cnt, fill, nsum, esum

    // CSR build + permuted index arrays (dst fixed per call)
    count_kernel<<<(E + 255) / 256, 256, 0, stream>>>(dst, cnt, E);
    scan_kernel<<<1, 1024, 0, stream>>>(cnt, offs, N);
    scatter_kernel<<<(E + 255) / 256, 256, 0, stream>>>(dst, src, offs, fill, csr,
                                                        srcp, dstp, E);

    // fused conversions / transposes
    const int prep_units = E * 32 + N * D / 4 + G * D / 4 + 512 * D + 384 * D;
    prep_kernel<<<(prep_units + 255) / 256, 256, 0, stream>>>(
        edge, node, node_bf, u, u_bf, We_w, Bt12, W3t, Wn_w, Wnt, N, G, E);

    const int edge_blocks = (E + 255) / 256;
    const int node_blocks = (N + 127) / 128;
    const int proj_blocks = (N + 127) / 128;
    const int red_blocks  = (N + 127) / 128;

    for (int pass = 0; pass < 3; ++pass) {
        uproj_kernel<<<G, 128, 0, stream>>>(u, We_w, We_b, upf);
        nproj_gemm<<<proj_blocks, 256, 0, stream>>>(node_bf, Bt12, upf, batch,
                                                    npb, npf2, N);
        edge_gemm<<<edge_blocks, 256, 0, stream>>>(edge_bf, csr, srcp, dstp,
                                                   npb, npf2, W3t, E, pass == 0 ? 1 : 0);
        gather_ebar<<<(N + 7) / 8, 256, 0, stream>>>(edge_bf, offs, ebar_bf, N);
        node_gemm<<<node_blocks, 256, 0, stream>>>(node_bf, ebar_bf, u_bf, batch,
                                                   Wnt, Wn_b, N);
        reduce_partial<<<red_blocks, 256, 0, stream>>>(node_bf, ebar_bf, batch, nsum, esum, N);
        finalize_global<<<G, 128, 0, stream>>>(nsum, esum, batch, nmean, emean,
                                               u, u_bf, Wg_w, Wg_b, N);
    }
    out_kernel<<<G, 384, 0, stream>>>(nmean, emean, u, batch, lin_w, lin_b,
                                      (float*)d_out, N, NC);
}